// Round 7
// baseline (371.529 us; speedup 1.0000x reference)
//
#include <hip/hip_runtime.h>
#include <cstdint>

typedef unsigned uint;
typedef unsigned short u16;
typedef int v4i  __attribute__((ext_vector_type(4)));
typedef int v16i __attribute__((ext_vector_type(16)));

// d_ws word layout:
//   [0,144)       w1 signs as +-1.0f
//   [144,1424)    W2B: conv2 B-frags, frag f=s*64+l, 4 words each (16 i8)
//   [1424,3728)   W3B: conv3 B-frags, frag f=s*64+l, 4 words each
//   [3728,8568)   wfc packed+expanded to 22x22 grid (10*484 words)
static constexpr int WS_W2B = 144;
static constexpr int WS_W3B = 1424;
static constexpr int WS_FC  = 3728;

// LDS regions (overlaid by phase lifetime):
//  A [0,18432):     xs float[784] (conv1 in)  ->  h2 i8[576][32] (conv2 out)
//  B [18432,29248): h1 i8[676][16] (conv1 out) -> h3 uint[484] (conv3 out)
//  C [29248,...):   red/lg
static constexpr int L_XS  = 0;
static constexpr int L_H2  = 0;
static constexpr int L_H1  = 18432;
static constexpr int L_H3  = 18432;
static constexpr int L_RED = 29248;  // uint[4][5]
static constexpr int L_LG  = 29328;  // float[10]
static constexpr int L_TOT = 29376;

__global__ __launch_bounds__(256) void pack_kernel(
    const float* __restrict__ w1, const float* __restrict__ w2,
    const float* __restrict__ w3, const float* __restrict__ wfc,
    uint* __restrict__ wsu)
{
    int gid = blockIdx.x * 256 + threadIdx.x;
    if (gid < 144) {
        ((float*)wsu)[gid] = (w1[gid] >= 0.f) ? 1.f : -1.f;
    } else if (gid < 464) {
        // conv2 B frag: oc = l&31, tap = 2s + (l>>5), ic = e (K = tap*16+ic)
        int f = gid - 144, s = f >> 6, l = f & 63;
        int oc = l & 31, tap = s * 2 + (l >> 5);
        uint w[4] = {0u, 0u, 0u, 0u};
        if (tap < 9) {
            for (int e = 0; e < 16; ++e) {
                uint b = (w2[(oc * 16 + e) * 9 + tap] >= 0.f) ? 0x01u : 0xFFu;
                w[e >> 2] |= b << (8 * (e & 3));
            }
        }
        for (int j = 0; j < 4; ++j) wsu[WS_W2B + f * 4 + j] = w[j];
    } else if (gid < 1040) {
        // conv3 B frag: oc = l&31, tap = s, ic = (l>>5)*16 + e (K = tap*32+ic)
        int f = gid - 464, s = f >> 6, l = f & 63;
        int oc = l & 31, icb = (l >> 5) * 16;
        uint w[4] = {0u, 0u, 0u, 0u};
        for (int e = 0; e < 16; ++e) {
            uint b = (w3[(oc * 32 + icb + e) * 9 + s] >= 0.f) ? 0x01u : 0xFFu;
            w[e >> 2] |= b << (8 * (e & 3));
        }
        for (int j = 0; j < 4; ++j) wsu[WS_W3B + f * 4 + j] = w[j];
    } else if (gid < 5880) {
        int f = gid - 1040, o = f / 484, p = f % 484;
        int Y = p / 22, X = p % 22;
        const float* base = wfc + o * 3872 + (Y >> 1) * 11 + (X >> 1);
        uint bits = 0;
        for (int c = 0; c < 32; ++c)
            bits |= (base[c * 121] >= 0.f ? 1u : 0u) << c;
        wsu[WS_FC + f] = bits;
    }
}

// 4 sign bits -> 4 i8 bytes (bit=1 -> +1, bit=0 -> -1)
__device__ __forceinline__ int expand4(uint t) {
    return (int)~(((t * 0x00204081u) & 0x01010101u) * 0xFEu);
}
__device__ __forceinline__ v4i expand16(uint bits) {
    v4i r;
    r[0] = expand4(bits & 0xFu);
    r[1] = expand4((bits >> 4) & 0xFu);
    r[2] = expand4((bits >> 8) & 0xFu);
    r[3] = expand4((bits >> 12) & 0xFu);
    return r;
}

__global__ __launch_bounds__(256) void binet_kernel(
    const float* __restrict__ x, const uint* __restrict__ wsu,
    const float* __restrict__ bfc, float* __restrict__ out)
{
    __shared__ __align__(16) unsigned char lds[L_TOT];
    const int t = threadIdx.x;
    const int img = blockIdx.x;
    const int l = t & 63, wave = t >> 6, half = l >> 5, lane31 = l & 31;

    float* xs = (float*)(lds + L_XS);
    signed char* h1 = (signed char*)(lds + L_H1);
    signed char* h2 = (signed char*)(lds + L_H2);
    uint* h3 = (uint*)(lds + L_H3);
    uint (*red)[5] = (uint(*)[5])(lds + L_RED);
    float* lg = (float*)(lds + L_LG);

    // ---- load image ----
    {
        const float* xin = x + (size_t)img * 784;
        for (int i = t; i < 784; i += 256) xs[i] = xin[i];
    }
    __syncthreads();

    // ---- conv1: fp32 fast path, rare fp64 fallback; i8 +-1 out (b128) ----
    {
        const float* wf = (const float*)wsu;   // uniform -> scalar loads
        const int p0 = t, p1 = t + 256, p2 = t + 512;
        const bool has2 = (p2 < 676);
        const int y0 = p0 / 26, x0 = p0 % 26;
        const int y1 = p1 / 26, x1 = p1 % 26;
        const int y2 = has2 ? p2 / 26 : 0, x2 = has2 ? p2 % 26 : 0;
        float xv0[9], xv1[9], xv2[9];
        #pragma unroll
        for (int ky = 0; ky < 3; ++ky)
            #pragma unroll
            for (int kx = 0; kx < 3; ++kx) {
                xv0[ky*3+kx] = xs[(y0+ky)*28 + x0 + kx];
                xv1[ky*3+kx] = xs[(y1+ky)*28 + x1 + kx];
                xv2[ky*3+kx] = xs[(y2+ky)*28 + x2 + kx];
            }
        uint m0 = 0, m1 = 0, m2 = 0;
        for (int oc = 0; oc < 16; ++oc) {
            float s0 = 0.f, s1 = 0.f, s2 = 0.f;
            #pragma unroll
            for (int k = 0; k < 9; ++k) {
                float w = wf[oc*9 + k];
                s0 = fmaf(xv0[k], w, s0);
                s1 = fmaf(xv1[k], w, s1);
                s2 = fmaf(xv2[k], w, s2);
            }
            bool b0 = (s0 >= 0.f), b1 = (s1 >= 0.f), b2 = (s2 >= 0.f);
            // fp32 accum error bound ~2.5e-5 << 1e-4: outside the band the
            // fp32 sign equals the exact (fp64) sign.
            if (__builtin_expect(fabsf(s0) < 1e-4f, 0)) {
                double sd = 0.0;
                for (int k = 0; k < 9; ++k) sd += (double)xv0[k] * (double)wf[oc*9+k];
                b0 = (sd >= 0.0);
            }
            if (__builtin_expect(fabsf(s1) < 1e-4f, 0)) {
                double sd = 0.0;
                for (int k = 0; k < 9; ++k) sd += (double)xv1[k] * (double)wf[oc*9+k];
                b1 = (sd >= 0.0);
            }
            if (__builtin_expect(fabsf(s2) < 1e-4f, 0)) {
                double sd = 0.0;
                for (int k = 0; k < 9; ++k) sd += (double)xv2[k] * (double)wf[oc*9+k];
                b2 = (sd >= 0.0);
            }
            m0 |= (uint)b0 << oc;
            m1 |= (uint)b1 << oc;
            m2 |= (uint)b2 << oc;
        }
        *(v4i*)(h1 + p0*16) = expand16(m0);
        *(v4i*)(h1 + p1*16) = expand16(m1);
        if (has2) *(v4i*)(h1 + p2*16) = expand16(m2);
    }
    __syncthreads();

    // ---- conv2 via i8 MFMA, tile-pair ILP: M=576, N=32, K=144 (pad 160) ----
    {
        const v4i* w2bp = (const v4i*)(wsu + WS_W2B);
        v4i b2f[5];
        #pragma unroll
        for (int s = 0; s < 5; ++s) b2f[s] = w2bp[s*64 + l];

        #pragma unroll
        for (int base = 0; base < 16; base += 8) {
            const int tA = base + wave, tB = tA + 4;
            const int rowA = tA*32 + lane31, rowB = tB*32 + lane31;
            const int yA = rowA / 24, xA = rowA % 24;
            const int yB = rowB / 24, xB = rowB % 24;
            v16i accA = {0,0,0,0,0,0,0,0,0,0,0,0,0,0,0,0};
            v16i accB = {0,0,0,0,0,0,0,0,0,0,0,0,0,0,0,0};
            #pragma unroll
            for (int s = 0; s < 5; ++s) {
                int tap = s*2 + half; if (tap > 8) tap = 8;  // B zeroed for tap 9
                int ky = tap / 3, kx = tap - ky*3;
                v4i aA = *(const v4i*)(h1 + ((yA+ky)*26 + xA+kx)*16);
                v4i aB = *(const v4i*)(h1 + ((yB+ky)*26 + xB+kx)*16);
                accA = __builtin_amdgcn_mfma_i32_32x32x32_i8(aA, b2f[s], accA, 0, 0, 0);
                accB = __builtin_amdgcn_mfma_i32_32x32x32_i8(aB, b2f[s], accB, 0, 0, 0);
            }
            #pragma unroll
            for (int r = 0; r < 16; ++r) {
                int rrA = tA*32 + (r & 3) + 8*(r >> 2) + 4*half;
                int rrB = tB*32 + (r & 3) + 8*(r >> 2) + 4*half;
                h2[rrA*32 + lane31] = (accA[r] >= 0) ? (signed char)1 : (signed char)-1;
                h2[rrB*32 + lane31] = (accB[r] >= 0) ? (signed char)1 : (signed char)-1;
            }
        }
        // tail tiles 16,17 on waves 0,1
        if (wave < 2) {
            const int tT = 16 + wave;
            const int row = tT*32 + lane31;
            const int y = row / 24, xx = row % 24;
            v16i acc = {0,0,0,0,0,0,0,0,0,0,0,0,0,0,0,0};
            #pragma unroll
            for (int s = 0; s < 5; ++s) {
                int tap = s*2 + half; if (tap > 8) tap = 8;
                int ky = tap / 3, kx = tap - ky*3;
                v4i a = *(const v4i*)(h1 + ((y+ky)*26 + xx+kx)*16);
                acc = __builtin_amdgcn_mfma_i32_32x32x32_i8(a, b2f[s], acc, 0, 0, 0);
            }
            #pragma unroll
            for (int r = 0; r < 16; ++r) {
                int rr = tT*32 + (r & 3) + 8*(r >> 2) + 4*half;
                h2[rr*32 + lane31] = (acc[r] >= 0) ? (signed char)1 : (signed char)-1;
            }
        }
    }
    __syncthreads();

    // ---- conv3 via i8 MFMA, tile-pair ILP: M=484 (pad 512), N=32, K=288 ----
    {
        const v4i* w3bp = (const v4i*)(wsu + WS_W3B);
        v4i b3f[9];
        #pragma unroll
        for (int s = 0; s < 9; ++s) b3f[s] = w3bp[s*64 + l];

        #pragma unroll
        for (int base = 0; base < 16; base += 8) {
            const int tA = base + wave, tB = tA + 4;
            int rowA = tA*32 + lane31, rowB = tB*32 + lane31;
            int prA = (rowA < 484) ? rowA : 483;
            int prB = (rowB < 484) ? rowB : 483;
            const int yA = prA / 22, xA = prA % 22;
            const int yB = prB / 22, xB = prB % 22;
            v16i accA = {0,0,0,0,0,0,0,0,0,0,0,0,0,0,0,0};
            v16i accB = {0,0,0,0,0,0,0,0,0,0,0,0,0,0,0,0};
            #pragma unroll
            for (int s = 0; s < 9; ++s) {
                const int ky = s / 3, kx = s - ky*3;
                v4i aA = *(const v4i*)(h2 + ((yA+ky)*24 + xA+kx)*32 + half*16);
                v4i aB = *(const v4i*)(h2 + ((yB+ky)*24 + xB+kx)*32 + half*16);
                accA = __builtin_amdgcn_mfma_i32_32x32x32_i8(aA, b3f[s], accA, 0, 0, 0);
                accB = __builtin_amdgcn_mfma_i32_32x32x32_i8(aB, b3f[s], accB, 0, 0, 0);
            }
            #pragma unroll
            for (int r = 0; r < 16; ++r) {
                unsigned long long mA = __ballot(accA[r] >= 0);
                unsigned long long mB = __ballot(accB[r] >= 0);
                int raA = tA*32 + (r & 3) + 8*(r >> 2);
                int raB = tB*32 + (r & 3) + 8*(r >> 2);
                if (l < 2) {
                    int aAddr = raA + 4*l;
                    uint vA = (l == 0) ? (uint)mA : (uint)(mA >> 32);
                    if (aAddr < 484) h3[aAddr] = vA;
                    int bAddr = raB + 4*l;
                    uint vB = (l == 0) ? (uint)mB : (uint)(mB >> 32);
                    if (bAddr < 484) h3[bAddr] = vB;
                }
            }
        }
    }
    __syncthreads();

    // ---- avgpool + FC as binary dot (pairs packed in u32 halves) ----
    uint acc5[5] = {0u, 0u, 0u, 0u, 0u};
    for (int p = t; p < 484; p += 256) {
        uint h = h3[p];
        const uint* wp = wsu + WS_FC + p;
        #pragma unroll
        for (int o = 0; o < 5; ++o)
            acc5[o] += (uint)__popc(h ^ wp[(2*o)*484])
                     + ((uint)__popc(h ^ wp[(2*o+1)*484]) << 16);
    }
    #pragma unroll
    for (int o = 0; o < 5; ++o) {
        uint v = acc5[o];
        v += __shfl_down(v, 32); v += __shfl_down(v, 16);
        v += __shfl_down(v, 8);  v += __shfl_down(v, 4);
        v += __shfl_down(v, 2);  v += __shfl_down(v, 1);
        acc5[o] = v;
    }
    if (l == 0) {
        #pragma unroll
        for (int o = 0; o < 5; ++o) red[wave][o] = acc5[o];
    }
    __syncthreads();
    if (t < 10) {
        uint S = 0;
        #pragma unroll
        for (int j = 0; j < 4; ++j) {
            uint w = red[j][t >> 1];
            S += (t & 1) ? (w >> 16) : (w & 0xFFFFu);
        }
        lg[t] = 0.25f * (float)(15488 - 2*(int)S) + bfc[t];
    }
    __syncthreads();
    if (t < 10) {
        float m = lg[0];
        #pragma unroll
        for (int o = 1; o < 10; ++o) m = fmaxf(m, lg[o]);
        float se = 0.f;
        #pragma unroll
        for (int o = 0; o < 10; ++o) se += expf(lg[o] - m);
        out[(size_t)img*10 + t] = lg[t] - m - logf(se);
    }
}

extern "C" void kernel_launch(void* const* d_in, const int* in_sizes, int n_in,
                              void* d_out, int out_size, void* d_ws, size_t ws_size,
                              hipStream_t stream)
{
    const float* x   = (const float*)d_in[0];
    const float* w1  = (const float*)d_in[1];
    const float* w2  = (const float*)d_in[2];
    const float* w3  = (const float*)d_in[3];
    const float* wfc = (const float*)d_in[4];
    const float* bfc = (const float*)d_in[5];
    float* out = (float*)d_out;
    uint* wsu  = (uint*)d_ws;

    const int B = in_sizes[0] / 784;   // 8192

    hipLaunchKernelGGL(pack_kernel, dim3(23), dim3(256), 0, stream,
                       w1, w2, w3, wfc, wsu);
    hipLaunchKernelGGL(binet_kernel, dim3(B), dim3(256), 0, stream,
                       x, wsu, bfc, out);
}

// Round 8
// 217.881 us; speedup vs baseline: 1.7052x; 1.7052x over previous
//
#include <hip/hip_runtime.h>
#include <cstdint>

typedef unsigned uint;
typedef int v4i  __attribute__((ext_vector_type(4)));
typedef int v16i __attribute__((ext_vector_type(16)));

// d_ws word layout:
//   [0,144)       w1 signs as +-1.0f
//   [144,1424)    W2B: conv2 B-frags, frag f=s*64+l, 4 words each (16 i8)
//   [1424,3728)   W3B: conv3 B-frags, frag f=s*64+l, 4 words each
//   [3728,8568)   wfc packed+expanded to 22x22 grid (10*484 words)
static constexpr int WS_W2B = 144;
static constexpr int WS_W3B = 1424;
static constexpr int WS_FC  = 3728;

// LDS regions (overlaid by phase lifetime):
//   [0,18432)      xs float[784] (conv1 in) -> h2 i8[576][32] (conv2 out)
//   [18432,29248)  h1 i8[676][16] (conv1 out) -> h3 uint[484] (conv3 out)
//   [29248,38464)  W3B staged conv3 B-frags (9216B, conflict-free b128)
//   [38464,...)    red/lg
static constexpr int L_XS  = 0;
static constexpr int L_H2  = 0;
static constexpr int L_H1  = 18432;
static constexpr int L_H3  = 18432;
static constexpr int L_W3B = 29248;
static constexpr int L_RED = 38464;  // uint[8][5]
static constexpr int L_LG  = 38624;  // float[10]
static constexpr int L_TOT = 38664;

__global__ __launch_bounds__(256) void pack_kernel(
    const float* __restrict__ w1, const float* __restrict__ w2,
    const float* __restrict__ w3, const float* __restrict__ wfc,
    uint* __restrict__ wsu)
{
    int gid = blockIdx.x * 256 + threadIdx.x;
    if (gid < 144) {
        ((float*)wsu)[gid] = (w1[gid] >= 0.f) ? 1.f : -1.f;
    } else if (gid < 464) {
        // conv2 B frag: oc = l&31, tap = 2s + (l>>5), ic = e (K = tap*16+ic)
        int f = gid - 144, s = f >> 6, l = f & 63;
        int oc = l & 31, tap = s * 2 + (l >> 5);
        uint w[4] = {0u, 0u, 0u, 0u};
        if (tap < 9) {
            for (int e = 0; e < 16; ++e) {
                uint b = (w2[(oc * 16 + e) * 9 + tap] >= 0.f) ? 0x01u : 0xFFu;
                w[e >> 2] |= b << (8 * (e & 3));
            }
        }
        for (int j = 0; j < 4; ++j) wsu[WS_W2B + f * 4 + j] = w[j];
    } else if (gid < 1040) {
        // conv3 B frag: oc = l&31, tap = s, ic = (l>>5)*16 + e (K = tap*32+ic)
        int f = gid - 464, s = f >> 6, l = f & 63;
        int oc = l & 31, icb = (l >> 5) * 16;
        uint w[4] = {0u, 0u, 0u, 0u};
        for (int e = 0; e < 16; ++e) {
            uint b = (w3[(oc * 32 + icb + e) * 9 + s] >= 0.f) ? 0x01u : 0xFFu;
            w[e >> 2] |= b << (8 * (e & 3));
        }
        for (int j = 0; j < 4; ++j) wsu[WS_W3B + f * 4 + j] = w[j];
    } else if (gid < 5880) {
        int f = gid - 1040, o = f / 484, p = f % 484;
        int Y = p / 22, X = p % 22;
        const float* base = wfc + o * 3872 + (Y >> 1) * 11 + (X >> 1);
        uint bits = 0;
        for (int c = 0; c < 32; ++c)
            bits |= (base[c * 121] >= 0.f ? 1u : 0u) << c;
        wsu[WS_FC + f] = bits;
    }
}

// 4 sign bits -> 4 i8 bytes (bit=1 -> +1, bit=0 -> -1)
__device__ __forceinline__ int expand4(uint t) {
    return (int)~(((t * 0x00204081u) & 0x01010101u) * 0xFEu);
}
__device__ __forceinline__ v4i expand16(uint bits) {
    v4i r;
    r[0] = expand4(bits & 0xFu);
    r[1] = expand4((bits >> 4) & 0xFu);
    r[2] = expand4((bits >> 8) & 0xFu);
    r[3] = expand4((bits >> 12) & 0xFu);
    return r;
}

__global__ __launch_bounds__(512) void binet_kernel(
    const float* __restrict__ x, const uint* __restrict__ wsu,
    const float* __restrict__ bfc, float* __restrict__ out)
{
    __shared__ __align__(16) unsigned char lds[L_TOT];
    const int t = threadIdx.x;
    const int img = blockIdx.x;
    const int l = t & 63, wave = t >> 6, half = l >> 5, lane31 = l & 31;

    float* xs = (float*)(lds + L_XS);
    signed char* h1 = (signed char*)(lds + L_H1);
    signed char* h2 = (signed char*)(lds + L_H2);
    uint* h3 = (uint*)(lds + L_H3);
    uint* w3l = (uint*)(lds + L_W3B);
    uint (*red)[5] = (uint(*)[5])(lds + L_RED);
    float* lg = (float*)(lds + L_LG);

    // ---- load image; stage conv3 B-frags into LDS (used after conv2) ----
    {
        const float* xin = x + (size_t)img * 784;
        for (int i = t; i < 784; i += 512) xs[i] = xin[i];
        for (int i = t; i < 2304; i += 512) w3l[i] = wsu[WS_W3B + i];
    }
    __syncthreads();

    // ---- conv1: fp32 fast path, rare fp64 fallback; i8 +-1 out (b128) ----
    // 676 positions over 512 threads: each thread 1-2 positions.
    {
        const float* wf = (const float*)wsu;   // uniform -> scalar loads
        const int p0 = t, p1 = t + 512;
        const bool has1 = (p1 < 676);
        const int y0 = p0 / 26, x0 = p0 % 26;
        const int y1 = has1 ? p1 / 26 : 0, x1 = has1 ? p1 % 26 : 0;
        float xv0[9], xv1[9];
        #pragma unroll
        for (int ky = 0; ky < 3; ++ky)
            #pragma unroll
            for (int kx = 0; kx < 3; ++kx) {
                xv0[ky*3+kx] = xs[(y0+ky)*28 + x0 + kx];
                xv1[ky*3+kx] = xs[(y1+ky)*28 + x1 + kx];
            }
        uint m0 = 0, m1 = 0;
        for (int oc = 0; oc < 16; ++oc) {
            float s0 = 0.f, s1 = 0.f;
            #pragma unroll
            for (int k = 0; k < 9; ++k) {
                float w = wf[oc*9 + k];
                s0 = fmaf(xv0[k], w, s0);
                s1 = fmaf(xv1[k], w, s1);
            }
            bool b0 = (s0 >= 0.f), b1 = (s1 >= 0.f);
            // fp32 accum error bound ~2.5e-5 << 1e-4: outside the band the
            // fp32 sign equals the exact (fp64) sign.
            if (__builtin_expect(fabsf(s0) < 1e-4f, 0)) {
                double sd = 0.0;
                for (int k = 0; k < 9; ++k) sd += (double)xv0[k] * (double)wf[oc*9+k];
                b0 = (sd >= 0.0);
            }
            if (__builtin_expect(fabsf(s1) < 1e-4f, 0)) {
                double sd = 0.0;
                for (int k = 0; k < 9; ++k) sd += (double)xv1[k] * (double)wf[oc*9+k];
                b1 = (sd >= 0.0);
            }
            m0 |= (uint)b0 << oc;
            m1 |= (uint)b1 << oc;
        }
        *(v4i*)(h1 + p0*16) = expand16(m0);
        if (has1) *(v4i*)(h1 + p1*16) = expand16(m1);
    }
    __syncthreads();

    // ---- conv2 via i8 MFMA: M=576, N=32, K=144 (pad 160) ----
    // A: direct b128 from h1. B: 5 frags in regs (phase-local ~52 VGPR).
    {
        const v4i* w2bp = (const v4i*)(wsu + WS_W2B);
        v4i b2f[5];
        #pragma unroll
        for (int s = 0; s < 5; ++s) b2f[s] = w2bp[s*64 + l];
        for (int tile = wave; tile < 18; tile += 8) {
            const int mb = tile * 32;
            const int row = mb + lane31;
            const int y = row / 24, xx = row % 24;
            v16i acc = {0,0,0,0,0,0,0,0,0,0,0,0,0,0,0,0};
            #pragma unroll
            for (int s = 0; s < 5; ++s) {
                int tap = s*2 + half; if (tap > 8) tap = 8;  // B zeroed for tap 9
                int ky = tap / 3, kx = tap - ky*3;
                v4i a = *(const v4i*)(h1 + ((y+ky)*26 + xx+kx)*16);
                acc = __builtin_amdgcn_mfma_i32_32x32x32_i8(a, b2f[s], acc, 0, 0, 0);
            }
            #pragma unroll
            for (int r = 0; r < 16; ++r) {
                int rr = mb + (r & 3) + 8*(r >> 2) + 4*half;
                h2[rr*32 + lane31] = (acc[r] >= 0) ? (signed char)1 : (signed char)-1;
            }
        }
    }
    __syncthreads();

    // ---- conv3 via i8 MFMA: M=484 (pad 512), N=32, K=288 ----
    // A: b128 from h2. B: per-MFMA b128 from staged LDS (keeps VGPR low).
    {
        const v4i* w3f = (const v4i*)(lds + L_W3B);
        for (int tile = wave; tile < 16; tile += 8) {
            const int mb = tile * 32;
            int row = mb + lane31;
            int pr = (row < 484) ? row : 483;
            const int y = pr / 22, xx = pr % 22;
            v16i acc = {0,0,0,0,0,0,0,0,0,0,0,0,0,0,0,0};
            #pragma unroll
            for (int s = 0; s < 9; ++s) {
                const int ky = s / 3, kx = s - ky*3;
                v4i a = *(const v4i*)(h2 + ((y+ky)*24 + xx+kx)*32 + half*16);
                v4i b = w3f[s*64 + l];
                acc = __builtin_amdgcn_mfma_i32_32x32x32_i8(a, b, acc, 0, 0, 0);
            }
            #pragma unroll
            for (int r = 0; r < 16; ++r) {
                unsigned long long mm = __ballot(acc[r] >= 0);
                int ra = mb + (r & 3) + 8*(r >> 2);
                if (l < 2) {
                    int addr = ra + 4*l;
                    if (addr < 484) {
                        uint val = (l == 0) ? (uint)mm : (uint)(mm >> 32);
                        h3[addr] = val;
                    }
                }
            }
        }
    }
    __syncthreads();

    // ---- avgpool + FC as binary dot (pairs packed in u32 halves) ----
    uint acc5[5] = {0u, 0u, 0u, 0u, 0u};
    for (int p = t; p < 484; p += 512) {
        uint h = h3[p];
        const uint* wp = wsu + WS_FC + p;
        #pragma unroll
        for (int o = 0; o < 5; ++o)
            acc5[o] += (uint)__popc(h ^ wp[(2*o)*484])
                     + ((uint)__popc(h ^ wp[(2*o+1)*484]) << 16);
    }
    #pragma unroll
    for (int o = 0; o < 5; ++o) {
        uint v = acc5[o];
        v += __shfl_down(v, 32); v += __shfl_down(v, 16);
        v += __shfl_down(v, 8);  v += __shfl_down(v, 4);
        v += __shfl_down(v, 2);  v += __shfl_down(v, 1);
        acc5[o] = v;
    }
    if (l == 0) {
        #pragma unroll
        for (int o = 0; o < 5; ++o) red[wave][o] = acc5[o];
    }
    __syncthreads();
    if (t < 10) {
        uint S = 0;
        #pragma unroll
        for (int j = 0; j < 8; ++j) {
            uint w = red[j][t >> 1];
            S += (t & 1) ? (w >> 16) : (w & 0xFFFFu);
        }
        lg[t] = 0.25f * (float)(15488 - 2*(int)S) + bfc[t];
    }
    __syncthreads();
    if (t < 10) {
        float m = lg[0];
        #pragma unroll
        for (int o = 1; o < 10; ++o) m = fmaxf(m, lg[o]);
        float se = 0.f;
        #pragma unroll
        for (int o = 0; o < 10; ++o) se += expf(lg[o] - m);
        out[(size_t)img*10 + t] = lg[t] - m - logf(se);
    }
}

extern "C" void kernel_launch(void* const* d_in, const int* in_sizes, int n_in,
                              void* d_out, int out_size, void* d_ws, size_t ws_size,
                              hipStream_t stream)
{
    const float* x   = (const float*)d_in[0];
    const float* w1  = (const float*)d_in[1];
    const float* w2  = (const float*)d_in[2];
    const float* w3  = (const float*)d_in[3];
    const float* wfc = (const float*)d_in[4];
    const float* bfc = (const float*)d_in[5];
    float* out = (float*)d_out;
    uint* wsu  = (uint*)d_ws;

    const int B = in_sizes[0] / 784;   // 8192

    hipLaunchKernelGGL(pack_kernel, dim3(23), dim3(256), 0, stream,
                       w1, w2, w3, wfc, wsu);
    hipLaunchKernelGGL(binet_kernel, dim3(B), dim3(512), 0, stream,
                       x, wsu, bfc, out);
}

// Round 9
// 160.385 us; speedup vs baseline: 2.3165x; 1.3585x over previous
//
#include <hip/hip_runtime.h>
#include <cstdint>

typedef unsigned uint;
typedef int v4i  __attribute__((ext_vector_type(4)));
typedef int v16i __attribute__((ext_vector_type(16)));

// d_ws word layout:
//   [0,144)       w1 signs as +-1.0f
//   [144,1424)    W2B: conv2 B-frags, frag f=s*64+l, 4 words each (16 i8)
//   [1424,3728)   W3B: conv3 B-frags, frag f=s*64+l, 4 words each
//   [3728,8568)   wfc packed+expanded to 22x22 grid (10*484 words)
static constexpr int WS_W2B = 144;
static constexpr int WS_W3B = 1424;
static constexpr int WS_FC  = 3728;

// LDS regions (overlaid by phase lifetime):
//   [0,18432)      xs float[784] (conv1 in) -> h2 i8[576][32] (expand out / conv3 in)
//   [18432,29248)  h1 i8[676][16] (conv1 out / conv2 in) -> h3 uint[484] (conv3 out)
//   [29248,31552)  h2b uint[576]  (conv2 ballot out / expand in)
//   [31552,...)    red/lg
static constexpr int L_XS  = 0;
static constexpr int L_H2  = 0;
static constexpr int L_H1  = 18432;
static constexpr int L_H3  = 18432;
static constexpr int L_H2B = 29248;
static constexpr int L_RED = 31552;  // uint[4][5]
static constexpr int L_LG  = 31632;  // float[10]
static constexpr int L_TOT = 31672;

__global__ __launch_bounds__(256) void pack_kernel(
    const float* __restrict__ w1, const float* __restrict__ w2,
    const float* __restrict__ w3, const float* __restrict__ wfc,
    uint* __restrict__ wsu)
{
    int gid = blockIdx.x * 256 + threadIdx.x;
    if (gid < 144) {
        ((float*)wsu)[gid] = (w1[gid] >= 0.f) ? 1.f : -1.f;
    } else if (gid < 464) {
        // conv2 B frag: oc = l&31, tap = 2s + (l>>5), ic = e (K = tap*16+ic)
        int f = gid - 144, s = f >> 6, l = f & 63;
        int oc = l & 31, tap = s * 2 + (l >> 5);
        uint w[4] = {0u, 0u, 0u, 0u};
        if (tap < 9) {
            for (int e = 0; e < 16; ++e) {
                uint b = (w2[(oc * 16 + e) * 9 + tap] >= 0.f) ? 0x01u : 0xFFu;
                w[e >> 2] |= b << (8 * (e & 3));
            }
        }
        for (int j = 0; j < 4; ++j) wsu[WS_W2B + f * 4 + j] = w[j];
    } else if (gid < 1040) {
        // conv3 B frag: oc = l&31, tap = s, ic = (l>>5)*16 + e (K = tap*32+ic)
        int f = gid - 464, s = f >> 6, l = f & 63;
        int oc = l & 31, icb = (l >> 5) * 16;
        uint w[4] = {0u, 0u, 0u, 0u};
        for (int e = 0; e < 16; ++e) {
            uint b = (w3[(oc * 32 + icb + e) * 9 + s] >= 0.f) ? 0x01u : 0xFFu;
            w[e >> 2] |= b << (8 * (e & 3));
        }
        for (int j = 0; j < 4; ++j) wsu[WS_W3B + f * 4 + j] = w[j];
    } else if (gid < 5880) {
        int f = gid - 1040, o = f / 484, p = f % 484;
        int Y = p / 22, X = p % 22;
        const float* base = wfc + o * 3872 + (Y >> 1) * 11 + (X >> 1);
        uint bits = 0;
        for (int c = 0; c < 32; ++c)
            bits |= (base[c * 121] >= 0.f ? 1u : 0u) << c;
        wsu[WS_FC + f] = bits;
    }
}

// 4 sign bits -> 4 i8 bytes (bit=1 -> +1, bit=0 -> -1)
__device__ __forceinline__ int expand4(uint t) {
    return (int)~(((t * 0x00204081u) & 0x01010101u) * 0xFEu);
}
__device__ __forceinline__ v4i expand16(uint bits) {
    v4i r;
    r[0] = expand4(bits & 0xFu);
    r[1] = expand4((bits >> 4) & 0xFu);
    r[2] = expand4((bits >> 8) & 0xFu);
    r[3] = expand4((bits >> 12) & 0xFu);
    return r;
}

__global__ __launch_bounds__(256) void binet_kernel(
    const float* __restrict__ x, const uint* __restrict__ wsu,
    const float* __restrict__ bfc, float* __restrict__ out)
{
    __shared__ __align__(16) unsigned char lds[L_TOT];
    const int t = threadIdx.x;
    const int img = blockIdx.x;
    const int l = t & 63, wave = t >> 6, half = l >> 5, lane31 = l & 31;

    float* xs = (float*)(lds + L_XS);
    signed char* h1 = (signed char*)(lds + L_H1);
    signed char* h2 = (signed char*)(lds + L_H2);
    uint* h2b = (uint*)(lds + L_H2B);
    uint* h3 = (uint*)(lds + L_H3);
    uint (*red)[5] = (uint(*)[5])(lds + L_RED);
    float* lg = (float*)(lds + L_LG);

    // ---- load image ----
    {
        const float* xin = x + (size_t)img * 784;
        for (int i = t; i < 784; i += 256) xs[i] = xin[i];
    }
    __syncthreads();

    // ---- conv1: fp32 fast path, rare fp64 fallback; i8 +-1 out (b128) ----
    // Pass 1: thread (g = t>>5, x = t&31) owns 3 vertical positions
    // (rows 3g..3g+2, col x) -> shared 5x3 window, shift-only addressing.
    {
        const float* wf = (const float*)wsu;   // uniform -> scalar loads
        const int xcol = t & 31, g = t >> 5;
        const int y0 = g * 3;
        if (xcol < 26) {
            float xv[5][3];
            #pragma unroll
            for (int r = 0; r < 5; ++r)
                #pragma unroll
                for (int c = 0; c < 3; ++c)
                    xv[r][c] = xs[(y0 + r)*28 + xcol + c];
            uint m0 = 0, m1 = 0, m2 = 0;
            for (int oc = 0; oc < 16; ++oc) {
                float s0 = 0.f, s1 = 0.f, s2 = 0.f;
                #pragma unroll
                for (int ky = 0; ky < 3; ++ky)
                    #pragma unroll
                    for (int kx = 0; kx < 3; ++kx) {
                        float w = wf[oc*9 + ky*3 + kx];
                        s0 = fmaf(xv[ky    ][kx], w, s0);
                        s1 = fmaf(xv[ky + 1][kx], w, s1);
                        s2 = fmaf(xv[ky + 2][kx], w, s2);
                    }
                bool b0 = (s0 >= 0.f), b1 = (s1 >= 0.f), b2 = (s2 >= 0.f);
                // fp32 accum error bound ~2.5e-5 << 1e-4: outside the band
                // the fp32 sign equals the exact (fp64) sign.
                if (__builtin_expect(fabsf(s0) < 1e-4f, 0)) {
                    double sd = 0.0;
                    for (int k = 0; k < 9; ++k)
                        sd += (double)xv[k/3][k%3] * (double)wf[oc*9+k];
                    b0 = (sd >= 0.0);
                }
                if (__builtin_expect(fabsf(s1) < 1e-4f, 0)) {
                    double sd = 0.0;
                    for (int k = 0; k < 9; ++k)
                        sd += (double)xv[k/3 + 1][k%3] * (double)wf[oc*9+k];
                    b1 = (sd >= 0.0);
                }
                if (__builtin_expect(fabsf(s2) < 1e-4f, 0)) {
                    double sd = 0.0;
                    for (int k = 0; k < 9; ++k)
                        sd += (double)xv[k/3 + 2][k%3] * (double)wf[oc*9+k];
                    b2 = (sd >= 0.0);
                }
                m0 |= (uint)b0 << oc;
                m1 |= (uint)b1 << oc;
                m2 |= (uint)b2 << oc;
            }
            *(v4i*)(h1 + ((y0    )*26 + xcol)*16) = expand16(m0);
            *(v4i*)(h1 + ((y0 + 1)*26 + xcol)*16) = expand16(m1);
            *(v4i*)(h1 + ((y0 + 2)*26 + xcol)*16) = expand16(m2);
        }
        // Pass 2: rows 24,25 (52 positions) on wave 0.
        if (t < 64 && xcol < 26) {
            const int y = 24 + g;   // g in {0,1}
            float xw[5][3];
            #pragma unroll
            for (int r = 0; r < 3; ++r)
                #pragma unroll
                for (int c = 0; c < 3; ++c)
                    xw[r][c] = xs[(y + r)*28 + xcol + c];
            uint m = 0;
            for (int oc = 0; oc < 16; ++oc) {
                float s = 0.f;
                #pragma unroll
                for (int ky = 0; ky < 3; ++ky)
                    #pragma unroll
                    for (int kx = 0; kx < 3; ++kx)
                        s = fmaf(xw[ky][kx], wf[oc*9 + ky*3 + kx], s);
                bool b = (s >= 0.f);
                if (__builtin_expect(fabsf(s) < 1e-4f, 0)) {
                    double sd = 0.0;
                    for (int k = 0; k < 9; ++k)
                        sd += (double)xw[k/3][k%3] * (double)wf[oc*9+k];
                    b = (sd >= 0.0);
                }
                m |= (uint)b << oc;
            }
            *(v4i*)(h1 + (y*26 + xcol)*16) = expand16(m);
        }
    }
    __syncthreads();

    // ---- conv2 via i8 MFMA: M=576, N=32, K=144 (pad 160) ----
    // A: direct b128 from h1. Epilogue: ballot -> packed words (cheap).
    {
        const v4i* w2bp = (const v4i*)(wsu + WS_W2B);
        v4i b2f[5];
        #pragma unroll
        for (int s = 0; s < 5; ++s) b2f[s] = w2bp[s*64 + l];
        for (int tile = wave; tile < 18; tile += 4) {
            const int mb = tile * 32;
            const int row = mb + lane31;
            const int y = row / 24, xx = row % 24;
            v16i acc = {0,0,0,0,0,0,0,0,0,0,0,0,0,0,0,0};
            #pragma unroll
            for (int s = 0; s < 5; ++s) {
                int tap = s*2 + half; if (tap > 8) tap = 8;  // B zeroed for tap 9
                int ky = tap / 3, kx = tap - ky*3;
                v4i a = *(const v4i*)(h1 + ((y+ky)*26 + xx+kx)*16);
                acc = __builtin_amdgcn_mfma_i32_32x32x32_i8(a, b2f[s], acc, 0, 0, 0);
            }
            #pragma unroll
            for (int r = 0; r < 16; ++r) {
                unsigned long long mm = __ballot(acc[r] >= 0);  // bit l = oc l
                int rr = mb + (r & 3) + 8*(r >> 2);
                if (l == 0) h2b[rr] = (uint)mm;
                if (l == 1) h2b[rr + 4] = (uint)(mm >> 32);
            }
        }
    }
    __syncthreads();

    // ---- expand h2b -> h2 i8[576][32] (once per position) ----
    for (int p = t; p < 576; p += 256) {
        uint w = h2b[p];
        *(v4i*)(h2 + p*32)      = expand16(w & 0xFFFFu);
        *(v4i*)(h2 + p*32 + 16) = expand16(w >> 16);
    }
    __syncthreads();

    // ---- conv3 via i8 MFMA: M=484 (pad 512), N=32, K=288 ----
    {
        const v4i* w3bp = (const v4i*)(wsu + WS_W3B);
        v4i b3f[9];
        #pragma unroll
        for (int s = 0; s < 9; ++s) b3f[s] = w3bp[s*64 + l];
        for (int tile = wave; tile < 16; tile += 4) {
            const int mb = tile * 32;
            int row = mb + lane31;
            int pr = (row < 484) ? row : 483;
            const int y = pr / 22, xx = pr % 22;
            v16i acc = {0,0,0,0,0,0,0,0,0,0,0,0,0,0,0,0};
            #pragma unroll
            for (int s = 0; s < 9; ++s) {
                const int ky = s / 3, kx = s - ky*3;
                v4i a = *(const v4i*)(h2 + ((y+ky)*24 + xx+kx)*32 + half*16);
                acc = __builtin_amdgcn_mfma_i32_32x32x32_i8(a, b3f[s], acc, 0, 0, 0);
            }
            #pragma unroll
            for (int r = 0; r < 16; ++r) {
                unsigned long long mm = __ballot(acc[r] >= 0);
                int ra = mb + (r & 3) + 8*(r >> 2);
                if (l == 0 && ra < 484) h3[ra] = (uint)mm;
                if (l == 1 && ra + 4 < 484) h3[ra + 4] = (uint)(mm >> 32);
            }
        }
    }
    __syncthreads();

    // ---- avgpool + FC as binary dot (pairs packed in u32 halves) ----
    uint acc5[5] = {0u, 0u, 0u, 0u, 0u};
    for (int p = t; p < 484; p += 256) {
        uint h = h3[p];
        const uint* wp = wsu + WS_FC + p;
        #pragma unroll
        for (int o = 0; o < 5; ++o)
            acc5[o] += (uint)__popc(h ^ wp[(2*o)*484])
                     + ((uint)__popc(h ^ wp[(2*o+1)*484]) << 16);
    }
    #pragma unroll
    for (int o = 0; o < 5; ++o) {
        uint v = acc5[o];
        v += __shfl_down(v, 32); v += __shfl_down(v, 16);
        v += __shfl_down(v, 8);  v += __shfl_down(v, 4);
        v += __shfl_down(v, 2);  v += __shfl_down(v, 1);
        acc5[o] = v;
    }
    if (l == 0) {
        #pragma unroll
        for (int o = 0; o < 5; ++o) red[wave][o] = acc5[o];
    }
    __syncthreads();
    if (t < 10) {
        uint S = 0;
        #pragma unroll
        for (int j = 0; j < 4; ++j) {
            uint w = red[j][t >> 1];
            S += (t & 1) ? (w >> 16) : (w & 0xFFFFu);
        }
        lg[t] = 0.25f * (float)(15488 - 2*(int)S) + bfc[t];
    }
    __syncthreads();
    if (t < 10) {
        float m = lg[0];
        #pragma unroll
        for (int o = 1; o < 10; ++o) m = fmaxf(m, lg[o]);
        float se = 0.f;
        #pragma unroll
        for (int o = 0; o < 10; ++o) se += expf(lg[o] - m);
        out[(size_t)img*10 + t] = lg[t] - m - logf(se);
    }
}

extern "C" void kernel_launch(void* const* d_in, const int* in_sizes, int n_in,
                              void* d_out, int out_size, void* d_ws, size_t ws_size,
                              hipStream_t stream)
{
    const float* x   = (const float*)d_in[0];
    const float* w1  = (const float*)d_in[1];
    const float* w2  = (const float*)d_in[2];
    const float* w3  = (const float*)d_in[3];
    const float* wfc = (const float*)d_in[4];
    const float* bfc = (const float*)d_in[5];
    float* out = (float*)d_out;
    uint* wsu  = (uint*)d_ws;

    const int B = in_sizes[0] / 784;   // 8192

    hipLaunchKernelGGL(pack_kernel, dim3(23), dim3(256), 0, stream,
                       w1, w2, w3, wfc, wsu);
    hipLaunchKernelGGL(binet_kernel, dim3(B), dim3(256), 0, stream,
                       x, wsu, bfc, out);
}

// Round 10
// 152.831 us; speedup vs baseline: 2.4310x; 1.0494x over previous
//
#include <hip/hip_runtime.h>
#include <cstdint>

typedef unsigned uint;
typedef int v4i  __attribute__((ext_vector_type(4)));
typedef int v16i __attribute__((ext_vector_type(16)));

// d_ws word layout:
//   [0,144)       w1 signs as +-1.0f
//   [144,1424)    W2B: conv2 B-frags, frag f=s*64+l, 4 words each (16 i8)
//   [1424,3728)   W3B: conv3 B-frags, frag f=s*64+l, 4 words each
//   [3728,8568)   wfc packed+expanded to 22x22 grid (10*484 words)
static constexpr int WS_W2B = 144;
static constexpr int WS_W3B = 1424;
static constexpr int WS_FC  = 3728;

// LDS regions (overlaid by phase lifetime):
//   [0,18432)      xs float[784] (conv1 in) -> h2 i8[2][576][16] half-split
//                  (expand out / conv3 in; 16B-stride = conflict-free)
//   [18432,29248)  h1 i8[676][16] (conv1 out / conv2 in) -> h3 uint[484]
//   [29248,31552)  h2b uint[576]  (conv2 ballot out / expand in)
//   [31552,...)    red/lg
static constexpr int L_XS  = 0;
static constexpr int L_H2  = 0;
static constexpr int L_H1  = 18432;
static constexpr int L_H3  = 18432;
static constexpr int L_H2B = 29248;
static constexpr int L_RED = 31552;  // uint[4][5]
static constexpr int L_LG  = 31632;  // float[10]
static constexpr int L_TOT = 31672;

__global__ __launch_bounds__(256) void pack_kernel(
    const float* __restrict__ w1, const float* __restrict__ w2,
    const float* __restrict__ w3, const float* __restrict__ wfc,
    uint* __restrict__ wsu)
{
    int gid = blockIdx.x * 256 + threadIdx.x;
    if (gid < 144) {
        ((float*)wsu)[gid] = (w1[gid] >= 0.f) ? 1.f : -1.f;
    } else if (gid < 464) {
        // conv2 B frag: oc = l&31, tap = 2s + (l>>5), ic = e (K = tap*16+ic)
        int f = gid - 144, s = f >> 6, l = f & 63;
        int oc = l & 31, tap = s * 2 + (l >> 5);
        uint w[4] = {0u, 0u, 0u, 0u};
        if (tap < 9) {
            for (int e = 0; e < 16; ++e) {
                uint b = (w2[(oc * 16 + e) * 9 + tap] >= 0.f) ? 0x01u : 0xFFu;
                w[e >> 2] |= b << (8 * (e & 3));
            }
        }
        for (int j = 0; j < 4; ++j) wsu[WS_W2B + f * 4 + j] = w[j];
    } else if (gid < 1040) {
        // conv3 B frag: oc = l&31, tap = s, ic = (l>>5)*16 + e (K = tap*32+ic)
        int f = gid - 464, s = f >> 6, l = f & 63;
        int oc = l & 31, icb = (l >> 5) * 16;
        uint w[4] = {0u, 0u, 0u, 0u};
        for (int e = 0; e < 16; ++e) {
            uint b = (w3[(oc * 32 + icb + e) * 9 + s] >= 0.f) ? 0x01u : 0xFFu;
            w[e >> 2] |= b << (8 * (e & 3));
        }
        for (int j = 0; j < 4; ++j) wsu[WS_W3B + f * 4 + j] = w[j];
    } else if (gid < 5880) {
        int f = gid - 1040, o = f / 484, p = f % 484;
        int Y = p / 22, X = p % 22;
        const float* base = wfc + o * 3872 + (Y >> 1) * 11 + (X >> 1);
        uint bits = 0;
        for (int c = 0; c < 32; ++c)
            bits |= (base[c * 121] >= 0.f ? 1u : 0u) << c;
        wsu[WS_FC + f] = bits;
    }
}

// 4 sign bits -> 4 i8 bytes (bit=1 -> +1, bit=0 -> -1)
__device__ __forceinline__ int expand4(uint t) {
    return (int)~(((t * 0x00204081u) & 0x01010101u) * 0xFEu);
}
__device__ __forceinline__ v4i expand16(uint bits) {
    v4i r;
    r[0] = expand4(bits & 0xFu);
    r[1] = expand4((bits >> 4) & 0xFu);
    r[2] = expand4((bits >> 8) & 0xFu);
    r[3] = expand4((bits >> 12) & 0xFu);
    return r;
}

__global__ __launch_bounds__(256) void binet_kernel(
    const float* __restrict__ x, const uint* __restrict__ wsu,
    const float* __restrict__ bfc, float* __restrict__ out)
{
    __shared__ __align__(16) unsigned char lds[L_TOT];
    const int t = threadIdx.x;
    const int img = blockIdx.x;
    const int l = t & 63, wave = t >> 6, half = l >> 5, lane31 = l & 31;

    float* xs = (float*)(lds + L_XS);
    signed char* h1 = (signed char*)(lds + L_H1);
    signed char* h2 = (signed char*)(lds + L_H2);
    uint* h2b = (uint*)(lds + L_H2B);
    uint* h3 = (uint*)(lds + L_H3);
    uint (*red)[5] = (uint(*)[5])(lds + L_RED);
    float* lg = (float*)(lds + L_LG);

    // ---- load image ----
    {
        const float* xin = x + (size_t)img * 784;
        for (int i = t; i < 784; i += 256) xs[i] = xin[i];
    }
    __syncthreads();

    // ---- conv1: fp32 fast path, single merged rare fp64 fallback ----
    // Pass 1: thread (g = t>>5, x = t&31) owns rows 3g..3g+2, col x.
    {
        const float* wf = (const float*)wsu;   // uniform -> scalar loads
        const int xcol = t & 31, g = t >> 5;
        const int y0 = g * 3;
        if (xcol < 26) {
            float xv[5][3];
            #pragma unroll
            for (int r = 0; r < 5; ++r)
                #pragma unroll
                for (int c = 0; c < 3; ++c)
                    xv[r][c] = xs[(y0 + r)*28 + xcol + c];
            uint m0 = 0, m1 = 0, m2 = 0;
            for (int oc = 0; oc < 16; ++oc) {
                float s0 = 0.f, s1 = 0.f, s2 = 0.f;
                #pragma unroll
                for (int ky = 0; ky < 3; ++ky)
                    #pragma unroll
                    for (int kx = 0; kx < 3; ++kx) {
                        float w = wf[oc*9 + ky*3 + kx];
                        s0 = fmaf(xv[ky    ][kx], w, s0);
                        s1 = fmaf(xv[ky + 1][kx], w, s1);
                        s2 = fmaf(xv[ky + 2][kx], w, s2);
                    }
                bool b0 = (s0 >= 0.f), b1 = (s1 >= 0.f), b2 = (s2 >= 0.f);
                // fp32 accum error bound ~2.5e-5 << 1e-4: outside the band
                // the fp32 sign equals the exact (fp64) sign.
                if (__builtin_expect((int)((fabsf(s0) < 1e-4f) |
                                           (fabsf(s1) < 1e-4f) |
                                           (fabsf(s2) < 1e-4f)), 0)) {
                    double d0 = 0.0, d1 = 0.0, d2 = 0.0;
                    for (int k = 0; k < 9; ++k) {
                        double w = (double)wf[oc*9 + k];
                        d0 += (double)xv[k/3    ][k%3] * w;
                        d1 += (double)xv[k/3 + 1][k%3] * w;
                        d2 += (double)xv[k/3 + 2][k%3] * w;
                    }
                    b0 = (d0 >= 0.0); b1 = (d1 >= 0.0); b2 = (d2 >= 0.0);
                }
                m0 |= (uint)b0 << oc;
                m1 |= (uint)b1 << oc;
                m2 |= (uint)b2 << oc;
            }
            *(v4i*)(h1 + ((y0    )*26 + xcol)*16) = expand16(m0);
            *(v4i*)(h1 + ((y0 + 1)*26 + xcol)*16) = expand16(m1);
            *(v4i*)(h1 + ((y0 + 2)*26 + xcol)*16) = expand16(m2);
        }
        // Pass 2: rows 24,25 (52 positions) on wave 0.
        if (t < 64 && xcol < 26) {
            const int y = 24 + g;   // g in {0,1}
            float xw[3][3];
            #pragma unroll
            for (int r = 0; r < 3; ++r)
                #pragma unroll
                for (int c = 0; c < 3; ++c)
                    xw[r][c] = xs[(y + r)*28 + xcol + c];
            uint m = 0;
            for (int oc = 0; oc < 16; ++oc) {
                float s = 0.f;
                #pragma unroll
                for (int ky = 0; ky < 3; ++ky)
                    #pragma unroll
                    for (int kx = 0; kx < 3; ++kx)
                        s = fmaf(xw[ky][kx], wf[oc*9 + ky*3 + kx], s);
                bool b = (s >= 0.f);
                if (__builtin_expect(fabsf(s) < 1e-4f, 0)) {
                    double sd = 0.0;
                    for (int k = 0; k < 9; ++k)
                        sd += (double)xw[k/3][k%3] * (double)wf[oc*9+k];
                    b = (sd >= 0.0);
                }
                m |= (uint)b << oc;
            }
            *(v4i*)(h1 + (y*26 + xcol)*16) = expand16(m);
        }
    }
    __syncthreads();

    // ---- conv2 via i8 MFMA: M=576, N=32, K=144 (pad 160) ----
    // A: direct b128 from h1 (16B-stride, conflict-free). Epilogue: ballot.
    {
        const v4i* w2bp = (const v4i*)(wsu + WS_W2B);
        v4i b2f[5];
        #pragma unroll
        for (int s = 0; s < 5; ++s) b2f[s] = w2bp[s*64 + l];
        for (int tile = wave; tile < 18; tile += 4) {
            const int mb = tile * 32;
            const int row = mb + lane31;
            const int y = row / 24, xx = row % 24;
            v16i acc = {0,0,0,0,0,0,0,0,0,0,0,0,0,0,0,0};
            #pragma unroll
            for (int s = 0; s < 5; ++s) {
                int tap = s*2 + half; if (tap > 8) tap = 8;  // B zeroed for tap 9
                int ky = tap / 3, kx = tap - ky*3;
                v4i a = *(const v4i*)(h1 + ((y+ky)*26 + xx+kx)*16);
                acc = __builtin_amdgcn_mfma_i32_32x32x32_i8(a, b2f[s], acc, 0, 0, 0);
            }
            #pragma unroll
            for (int r = 0; r < 16; ++r) {
                unsigned long long mm = __ballot(acc[r] >= 0);  // bit l = oc l
                int rr = mb + (r & 3) + 8*(r >> 2);
                if (l == 0) h2b[rr] = (uint)mm;
                if (l == 1) h2b[rr + 4] = (uint)(mm >> 32);
            }
        }
    }
    __syncthreads();

    // ---- expand h2b -> h2 i8[2][576][16] half-split (conflict-free) ----
    for (int p = t; p < 576; p += 256) {
        uint w = h2b[p];
        *(v4i*)(h2 + p*16)        = expand16(w & 0xFFFFu);   // ic 0-15
        *(v4i*)(h2 + 9216 + p*16) = expand16(w >> 16);       // ic 16-31
    }
    __syncthreads();

    // ---- conv3 via i8 MFMA: M=484 (pad 512), N=32, K=288 ----
    // A: b128 from half-split h2 (16B-stride per half-wave, conflict-free).
    {
        const v4i* w3bp = (const v4i*)(wsu + WS_W3B);
        v4i b3f[9];
        #pragma unroll
        for (int s = 0; s < 9; ++s) b3f[s] = w3bp[s*64 + l];
        const signed char* h2h = h2 + half*9216;
        for (int tile = wave; tile < 16; tile += 4) {
            const int mb = tile * 32;
            int row = mb + lane31;
            int pr = (row < 484) ? row : 483;
            const int y = pr / 22, xx = pr % 22;
            v16i acc = {0,0,0,0,0,0,0,0,0,0,0,0,0,0,0,0};
            #pragma unroll
            for (int s = 0; s < 9; ++s) {
                const int ky = s / 3, kx = s - ky*3;
                v4i a = *(const v4i*)(h2h + ((y+ky)*24 + xx+kx)*16);
                acc = __builtin_amdgcn_mfma_i32_32x32x32_i8(a, b3f[s], acc, 0, 0, 0);
            }
            #pragma unroll
            for (int r = 0; r < 16; ++r) {
                unsigned long long mm = __ballot(acc[r] >= 0);
                int ra = mb + (r & 3) + 8*(r >> 2);
                if (l == 0 && ra < 484) h3[ra] = (uint)mm;
                if (l == 1 && ra + 4 < 484) h3[ra + 4] = (uint)(mm >> 32);
            }
        }
    }
    __syncthreads();

    // ---- avgpool + FC as binary dot (pairs packed in u32 halves) ----
    uint acc5[5] = {0u, 0u, 0u, 0u, 0u};
    for (int p = t; p < 484; p += 256) {
        uint h = h3[p];
        const uint* wp = wsu + WS_FC + p;
        #pragma unroll
        for (int o = 0; o < 5; ++o)
            acc5[o] += (uint)__popc(h ^ wp[(2*o)*484])
                     + ((uint)__popc(h ^ wp[(2*o+1)*484]) << 16);
    }
    #pragma unroll
    for (int o = 0; o < 5; ++o) {
        uint v = acc5[o];
        v += __shfl_down(v, 32); v += __shfl_down(v, 16);
        v += __shfl_down(v, 8);  v += __shfl_down(v, 4);
        v += __shfl_down(v, 2);  v += __shfl_down(v, 1);
        acc5[o] = v;
    }
    if (l == 0) {
        #pragma unroll
        for (int o = 0; o < 5; ++o) red[wave][o] = acc5[o];
    }
    __syncthreads();
    if (t < 10) {
        uint S = 0;
        #pragma unroll
        for (int j = 0; j < 4; ++j) {
            uint w = red[j][t >> 1];
            S += (t & 1) ? (w >> 16) : (w & 0xFFFFu);
        }
        lg[t] = 0.25f * (float)(15488 - 2*(int)S) + bfc[t];
    }
    __syncthreads();
    if (t < 10) {
        float m = lg[0];
        #pragma unroll
        for (int o = 1; o < 10; ++o) m = fmaxf(m, lg[o]);
        float se = 0.f;
        #pragma unroll
        for (int o = 0; o < 10; ++o) se += expf(lg[o] - m);
        out[(size_t)img*10 + t] = lg[t] - m - logf(se);
    }
}

extern "C" void kernel_launch(void* const* d_in, const int* in_sizes, int n_in,
                              void* d_out, int out_size, void* d_ws, size_t ws_size,
                              hipStream_t stream)
{
    const float* x   = (const float*)d_in[0];
    const float* w1  = (const float*)d_in[1];
    const float* w2  = (const float*)d_in[2];
    const float* w3  = (const float*)d_in[3];
    const float* wfc = (const float*)d_in[4];
    const float* bfc = (const float*)d_in[5];
    float* out = (float*)d_out;
    uint* wsu  = (uint*)d_ws;

    const int B = in_sizes[0] / 784;   // 8192

    hipLaunchKernelGGL(pack_kernel, dim3(23), dim3(256), 0, stream,
                       w1, w2, w3, wfc, wsu);
    hipLaunchKernelGGL(binet_kernel, dim3(B), dim3(256), 0, stream,
                       x, wsu, bfc, out);
}

// Round 11
// 138.968 us; speedup vs baseline: 2.6735x; 1.0998x over previous
//
#include <hip/hip_runtime.h>
#include <cstdint>

typedef unsigned uint;
typedef int v4i  __attribute__((ext_vector_type(4)));
typedef int v16i __attribute__((ext_vector_type(16)));

// d_ws word layout:
//   [0,144)       w1 signs as +-1.0f
//   [144,1424)    W2B: conv2 B-frags, frag f=s*64+l, 4 words each (16 i8)
//   [1424,3728)   W3B: conv3 B-frags, frag f=s*64+l, 4 words each
//   [3728,8568)   wfc packed+expanded to 22x22 grid (10*484 words)
static constexpr int WS_W2B = 144;
static constexpr int WS_W3B = 1424;
static constexpr int WS_FC  = 3728;

// LDS layout, 20.9KB total -> 7 blocks/CU (was 31.7KB -> 5).
// Region A [0,18432): xs[0,3136) + h1[3136,13952) live through conv2;
//   both dead before expand writes h2 i8[2][576][16] over [0,18432).
// Region B [18432,20736): h2b uint[576] (conv2 out / expand in) ->
//   h3 uint[484] (conv3 out / FC in). Lifetimes disjoint (barriers).
static constexpr int L_XS  = 0;
static constexpr int L_H1  = 3136;
static constexpr int L_H2  = 0;
static constexpr int L_H2B = 18432;
static constexpr int L_H3  = 18432;
static constexpr int L_RED = 20736;  // uint[4][5]
static constexpr int L_LG  = 20816;  // float[10]
static constexpr int L_TOT = 20856;

__global__ __launch_bounds__(256) void pack_kernel(
    const float* __restrict__ w1, const float* __restrict__ w2,
    const float* __restrict__ w3, const float* __restrict__ wfc,
    uint* __restrict__ wsu)
{
    int gid = blockIdx.x * 256 + threadIdx.x;
    if (gid < 144) {
        ((float*)wsu)[gid] = (w1[gid] >= 0.f) ? 1.f : -1.f;
    } else if (gid < 464) {
        // conv2 B frag: oc = l&31, tap = 2s + (l>>5), ic = e (K = tap*16+ic)
        int f = gid - 144, s = f >> 6, l = f & 63;
        int oc = l & 31, tap = s * 2 + (l >> 5);
        uint w[4] = {0u, 0u, 0u, 0u};
        if (tap < 9) {
            for (int e = 0; e < 16; ++e) {
                uint b = (w2[(oc * 16 + e) * 9 + tap] >= 0.f) ? 0x01u : 0xFFu;
                w[e >> 2] |= b << (8 * (e & 3));
            }
        }
        for (int j = 0; j < 4; ++j) wsu[WS_W2B + f * 4 + j] = w[j];
    } else if (gid < 1040) {
        // conv3 B frag: oc = l&31, tap = s, ic = (l>>5)*16 + e (K = tap*32+ic)
        int f = gid - 464, s = f >> 6, l = f & 63;
        int oc = l & 31, icb = (l >> 5) * 16;
        uint w[4] = {0u, 0u, 0u, 0u};
        for (int e = 0; e < 16; ++e) {
            uint b = (w3[(oc * 32 + icb + e) * 9 + s] >= 0.f) ? 0x01u : 0xFFu;
            w[e >> 2] |= b << (8 * (e & 3));
        }
        for (int j = 0; j < 4; ++j) wsu[WS_W3B + f * 4 + j] = w[j];
    } else if (gid < 5880) {
        int f = gid - 1040, o = f / 484, p = f % 484;
        int Y = p / 22, X = p % 22;
        const float* base = wfc + o * 3872 + (Y >> 1) * 11 + (X >> 1);
        uint bits = 0;
        for (int c = 0; c < 32; ++c)
            bits |= (base[c * 121] >= 0.f ? 1u : 0u) << c;
        wsu[WS_FC + f] = bits;
    }
}

// 4 sign bits -> 4 i8 bytes (bit=1 -> +1, bit=0 -> -1)
__device__ __forceinline__ int expand4(uint t) {
    return (int)~(((t * 0x00204081u) & 0x01010101u) * 0xFEu);
}
__device__ __forceinline__ v4i expand16(uint bits) {
    v4i r;
    r[0] = expand4(bits & 0xFu);
    r[1] = expand4((bits >> 4) & 0xFu);
    r[2] = expand4((bits >> 8) & 0xFu);
    r[3] = expand4((bits >> 12) & 0xFu);
    return r;
}

__global__ __launch_bounds__(256) void binet_kernel(
    const float* __restrict__ x, const uint* __restrict__ wsu,
    const float* __restrict__ bfc, float* __restrict__ out)
{
    __shared__ __align__(16) unsigned char lds[L_TOT];
    const int t = threadIdx.x;
    const int img = blockIdx.x;
    const int l = t & 63, wave = t >> 6, half = l >> 5, lane31 = l & 31;

    float* xs = (float*)(lds + L_XS);
    signed char* h1 = (signed char*)(lds + L_H1);
    signed char* h2 = (signed char*)(lds + L_H2);
    uint* h2b = (uint*)(lds + L_H2B);
    uint* h3 = (uint*)(lds + L_H3);
    uint (*red)[5] = (uint(*)[5])(lds + L_RED);
    float* lg = (float*)(lds + L_LG);

    // ---- load image ----
    {
        const float* xin = x + (size_t)img * 784;
        for (int i = t; i < 784; i += 256) xs[i] = xin[i];
    }
    __syncthreads();

    // ---- conv1: single pass, thread (g = t/26, xcol = t%26) owns rows
    // 3g..3g+2, col xcol (g=8 owns rows 24,25). fp32 fast path + merged
    // rare fp64 fallback.
    if (t < 234) {
        const float* wf = (const float*)wsu;   // uniform -> scalar loads
        const int g = t / 26, xcol = t - g * 26;
        const int y0 = 3 * g;
        float xv[5][3];
        #pragma unroll
        for (int r = 0; r < 5; ++r) {
            int rr = y0 + r; if (rr > 27) rr = 27;   // g=8 clamp (rows unused)
            #pragma unroll
            for (int c = 0; c < 3; ++c)
                xv[r][c] = xs[rr*28 + xcol + c];
        }
        uint m0 = 0, m1 = 0, m2 = 0;
        for (int oc = 0; oc < 16; ++oc) {
            float s0 = 0.f, s1 = 0.f, s2 = 0.f;
            #pragma unroll
            for (int ky = 0; ky < 3; ++ky)
                #pragma unroll
                for (int kx = 0; kx < 3; ++kx) {
                    float w = wf[oc*9 + ky*3 + kx];
                    s0 = fmaf(xv[ky    ][kx], w, s0);
                    s1 = fmaf(xv[ky + 1][kx], w, s1);
                    s2 = fmaf(xv[ky + 2][kx], w, s2);
                }
            bool b0 = (s0 >= 0.f), b1 = (s1 >= 0.f), b2 = (s2 >= 0.f);
            // fp32 accum error bound ~2.5e-5 << 1e-4: outside the band the
            // fp32 sign equals the exact (fp64) sign.
            if (__builtin_expect((int)((fabsf(s0) < 1e-4f) |
                                       (fabsf(s1) < 1e-4f) |
                                       (fabsf(s2) < 1e-4f)), 0)) {
                double d0 = 0.0, d1 = 0.0, d2 = 0.0;
                for (int k = 0; k < 9; ++k) {
                    double w = (double)wf[oc*9 + k];
                    d0 += (double)xv[k/3    ][k%3] * w;
                    d1 += (double)xv[k/3 + 1][k%3] * w;
                    d2 += (double)xv[k/3 + 2][k%3] * w;
                }
                b0 = (d0 >= 0.0); b1 = (d1 >= 0.0); b2 = (d2 >= 0.0);
            }
            m0 |= (uint)b0 << oc;
            m1 |= (uint)b1 << oc;
            m2 |= (uint)b2 << oc;
        }
        *(v4i*)(h1 + ((y0    )*26 + xcol)*16) = expand16(m0);
        *(v4i*)(h1 + ((y0 + 1)*26 + xcol)*16) = expand16(m1);
        if (y0 + 2 <= 25)
            *(v4i*)(h1 + ((y0 + 2)*26 + xcol)*16) = expand16(m2);
    }
    __syncthreads();

    // ---- conv2 via i8 MFMA: M=576, N=32, K=144 (pad 160) ----
    // A: direct b128 from h1 (16B-stride, conflict-free). Epilogue: ballot.
    {
        const v4i* w2bp = (const v4i*)(wsu + WS_W2B);
        v4i b2f[5];
        #pragma unroll
        for (int s = 0; s < 5; ++s) b2f[s] = w2bp[s*64 + l];
        for (int tile = wave; tile < 18; tile += 4) {
            const int mb = tile * 32;
            const int row = mb + lane31;
            const int y = row / 24, xx = row % 24;
            v16i acc = {0,0,0,0,0,0,0,0,0,0,0,0,0,0,0,0};
            #pragma unroll
            for (int s = 0; s < 5; ++s) {
                int tap = s*2 + half; if (tap > 8) tap = 8;  // B zeroed for tap 9
                int ky = tap / 3, kx = tap - ky*3;
                v4i a = *(const v4i*)(h1 + ((y+ky)*26 + xx+kx)*16);
                acc = __builtin_amdgcn_mfma_i32_32x32x32_i8(a, b2f[s], acc, 0, 0, 0);
            }
            #pragma unroll
            for (int r = 0; r < 16; ++r) {
                unsigned long long mm = __ballot(acc[r] >= 0);  // bit l = oc l
                int rr = mb + (r & 3) + 8*(r >> 2);
                if (l == 0) h2b[rr] = (uint)mm;
                if (l == 1) h2b[rr + 4] = (uint)(mm >> 32);
            }
        }
    }
    __syncthreads();

    // ---- expand h2b -> h2 i8[2][576][16] half-split over region A ----
    for (int p = t; p < 576; p += 256) {
        uint w = h2b[p];
        *(v4i*)(h2 + p*16)        = expand16(w & 0xFFFFu);   // ic 0-15
        *(v4i*)(h2 + 9216 + p*16) = expand16(w >> 16);       // ic 16-31
    }
    __syncthreads();

    // ---- conv3 via i8 MFMA: M=484 (pad 512), N=32, K=288 ----
    // A: b128 from half-split h2 (16B-stride per half-wave, conflict-free).
    {
        const v4i* w3bp = (const v4i*)(wsu + WS_W3B);
        v4i b3f[9];
        #pragma unroll
        for (int s = 0; s < 9; ++s) b3f[s] = w3bp[s*64 + l];
        const signed char* h2h = h2 + half*9216;
        for (int tile = wave; tile < 16; tile += 4) {
            const int mb = tile * 32;
            int row = mb + lane31;
            int pr = (row < 484) ? row : 483;
            const int y = pr / 22, xx = pr % 22;
            v16i acc = {0,0,0,0,0,0,0,0,0,0,0,0,0,0,0,0};
            #pragma unroll
            for (int s = 0; s < 9; ++s) {
                const int ky = s / 3, kx = s - ky*3;
                v4i a = *(const v4i*)(h2h + ((y+ky)*24 + xx+kx)*16);
                acc = __builtin_amdgcn_mfma_i32_32x32x32_i8(a, b3f[s], acc, 0, 0, 0);
            }
            #pragma unroll
            for (int r = 0; r < 16; ++r) {
                unsigned long long mm = __ballot(acc[r] >= 0);
                int ra = mb + (r & 3) + 8*(r >> 2);
                if (l == 0 && ra < 484) h3[ra] = (uint)mm;
                if (l == 1 && ra + 4 < 484) h3[ra + 4] = (uint)(mm >> 32);
            }
        }
    }
    __syncthreads();

    // ---- avgpool + FC as binary dot (pairs packed in u32 halves) ----
    uint acc5[5] = {0u, 0u, 0u, 0u, 0u};
    for (int p = t; p < 484; p += 256) {
        uint h = h3[p];
        const uint* wp = wsu + WS_FC + p;
        #pragma unroll
        for (int o = 0; o < 5; ++o)
            acc5[o] += (uint)__popc(h ^ wp[(2*o)*484])
                     + ((uint)__popc(h ^ wp[(2*o+1)*484]) << 16);
    }
    #pragma unroll
    for (int o = 0; o < 5; ++o) {
        uint v = acc5[o];
        v += __shfl_down(v, 32); v += __shfl_down(v, 16);
        v += __shfl_down(v, 8);  v += __shfl_down(v, 4);
        v += __shfl_down(v, 2);  v += __shfl_down(v, 1);
        acc5[o] = v;
    }
    if (l == 0) {
        #pragma unroll
        for (int o = 0; o < 5; ++o) red[wave][o] = acc5[o];
    }
    __syncthreads();
    if (t < 10) {
        uint S = 0;
        #pragma unroll
        for (int j = 0; j < 4; ++j) {
            uint w = red[j][t >> 1];
            S += (t & 1) ? (w >> 16) : (w & 0xFFFFu);
        }
        lg[t] = 0.25f * (float)(15488 - 2*(int)S) + bfc[t];
    }
    __syncthreads();
    if (t < 10) {
        float m = lg[0];
        #pragma unroll
        for (int o = 1; o < 10; ++o) m = fmaxf(m, lg[o]);
        float se = 0.f;
        #pragma unroll
        for (int o = 0; o < 10; ++o) se += expf(lg[o] - m);
        out[(size_t)img*10 + t] = lg[t] - m - logf(se);
    }
}

extern "C" void kernel_launch(void* const* d_in, const int* in_sizes, int n_in,
                              void* d_out, int out_size, void* d_ws, size_t ws_size,
                              hipStream_t stream)
{
    const float* x   = (const float*)d_in[0];
    const float* w1  = (const float*)d_in[1];
    const float* w2  = (const float*)d_in[2];
    const float* w3  = (const float*)d_in[3];
    const float* wfc = (const float*)d_in[4];
    const float* bfc = (const float*)d_in[5];
    float* out = (float*)d_out;
    uint* wsu  = (uint*)d_ws;

    const int B = in_sizes[0] / 784;   // 8192

    hipLaunchKernelGGL(pack_kernel, dim3(23), dim3(256), 0, stream,
                       w1, w2, w3, wfc, wsu);
    hipLaunchKernelGGL(binet_kernel, dim3(B), dim3(256), 0, stream,
                       x, wsu, bfc, out);
}

// Round 12
// 109.777 us; speedup vs baseline: 3.3844x; 1.2659x over previous
//
#include <hip/hip_runtime.h>
#include <cstdint>

typedef unsigned uint;
typedef unsigned short u16;
typedef int v4i  __attribute__((ext_vector_type(4)));
typedef int v16i __attribute__((ext_vector_type(16)));
typedef float v2f __attribute__((ext_vector_type(2)));

// d_ws word layout:
//   [0,144)       w1 signs as +-1.0f
//   [144,1424)    W2B: conv2 weight frags, f=s*64+l: oc=l&31, tap=2s+(l>>5), ic=e
//   [1424,3728)   W3B: conv3 weight frags, f=s*64+l: oc=l&31, tap=s, ic=(l>>5)*16+e
//   [3728,8568)   wfc packed to 22x22 grid, PERMUTED bit order (see bitpos)
static constexpr int WS_W2B = 144;
static constexpr int WS_W3B = 1424;
static constexpr int WS_FC  = 3728;

// LDS layout, 20.9KB -> 7 blocks/CU (same as R11).
// Region A [0,18432): xs[0,3136)+h1[3136,13952) -> h2 i8[2][576][16]
// Region B [18432,20736): h2w u16[576][2] (conv2 out) -> h3 u32[484] (conv3 out)
static constexpr int L_XS  = 0;
static constexpr int L_H1  = 3136;
static constexpr int L_H2  = 0;
static constexpr int L_H2B = 18432;
static constexpr int L_H3  = 18432;
static constexpr int L_RED = 20736;  // uint[4][5]
static constexpr int L_LG  = 20816;  // float[10]
static constexpr int L_TOT = 20856;

// Permuted bit position for channel c in h2w/h3 words:
// lane-half h = c[2], reg r = (c&3) + 4*(c>>3); bitpos = 16h + r.
__device__ __host__ __forceinline__ int bitpos32(int c) {
    return (((c >> 2) & 1) << 4) + (c & 3) + ((c >> 3) << 2);
}

__global__ __launch_bounds__(256) void pack_kernel(
    const float* __restrict__ w1, const float* __restrict__ w2,
    const float* __restrict__ w3, const float* __restrict__ wfc,
    uint* __restrict__ wsu)
{
    int gid = blockIdx.x * 256 + threadIdx.x;
    if (gid < 144) {
        ((float*)wsu)[gid] = (w1[gid] >= 0.f) ? 1.f : -1.f;
    } else if (gid < 464) {
        // conv2 weight frag (A-operand): oc = l&31, tap = 2s+(l>>5), ic = e
        int f = gid - 144, s = f >> 6, l = f & 63;
        int oc = l & 31, tap = s * 2 + (l >> 5);
        uint w[4] = {0u, 0u, 0u, 0u};
        if (tap < 9) {
            for (int e = 0; e < 16; ++e) {
                uint b = (w2[(oc * 16 + e) * 9 + tap] >= 0.f) ? 0x01u : 0xFFu;
                w[e >> 2] |= b << (8 * (e & 3));
            }
        }
        for (int j = 0; j < 4; ++j) wsu[WS_W2B + f * 4 + j] = w[j];
    } else if (gid < 1040) {
        // conv3 weight frag (A-operand): oc = l&31, tap = s, ic = (l>>5)*16+e
        int f = gid - 464, s = f >> 6, l = f & 63;
        int oc = l & 31, icb = (l >> 5) * 16;
        uint w[4] = {0u, 0u, 0u, 0u};
        for (int e = 0; e < 16; ++e) {
            uint b = (w3[(oc * 32 + icb + e) * 9 + s] >= 0.f) ? 0x01u : 0xFFu;
            w[e >> 2] |= b << (8 * (e & 3));
        }
        for (int j = 0; j < 4; ++j) wsu[WS_W3B + f * 4 + j] = w[j];
    } else if (gid < 5880) {
        // FC weights, bit order matching conv3's per-lane mask build.
        int f = gid - 1040, o = f / 484, p = f % 484;
        int Y = p / 22, X = p % 22;
        const float* base = wfc + o * 3872 + (Y >> 1) * 11 + (X >> 1);
        uint bits = 0;
        for (int c = 0; c < 32; ++c)
            bits |= (base[c * 121] >= 0.f ? 1u : 0u) << bitpos32(c);
        wsu[WS_FC + f] = bits;
    }
}

// 4 sign bits -> 4 i8 bytes (bit=1 -> +1, bit=0 -> -1)
__device__ __forceinline__ int expand4(uint t) {
    return (int)~(((t * 0x00204081u) & 0x01010101u) * 0xFEu);
}
__device__ __forceinline__ v4i expand16(uint bits) {
    v4i r;
    r[0] = expand4(bits & 0xFu);
    r[1] = expand4((bits >> 4) & 0xFu);
    r[2] = expand4((bits >> 8) & 0xFu);
    r[3] = expand4((bits >> 12) & 0xFu);
    return r;
}

__global__ __launch_bounds__(256) void binet_kernel(
    const float* __restrict__ x, const uint* __restrict__ wsu,
    const float* __restrict__ bfc, float* __restrict__ out)
{
    __shared__ __align__(16) unsigned char lds[L_TOT];
    const int t = threadIdx.x;
    const int img = blockIdx.x;
    const int l = t & 63, wave = t >> 6, half = l >> 5, lane31 = l & 31;

    float* xs = (float*)(lds + L_XS);
    signed char* h1 = (signed char*)(lds + L_H1);
    signed char* h2 = (signed char*)(lds + L_H2);
    u16*  h2u = (u16*)(lds + L_H2B);
    uint* h2w = (uint*)(lds + L_H2B);
    u16*  h3u = (u16*)(lds + L_H3);
    uint* h3  = (uint*)(lds + L_H3);
    uint (*red)[5] = (uint(*)[5])(lds + L_RED);
    float* lg = (float*)(lds + L_LG);

    // ---- load image ----
    {
        const float* xin = x + (size_t)img * 784;
        for (int i = t; i < 784; i += 256) xs[i] = xin[i];
    }
    __syncthreads();

    // ---- conv1: packed-f32 fast path (v_pk_fma), merged rare fp64 fallback.
    // Thread (g = t/26, xcol = t%26) owns rows 3g..3g+2, col xcol.
    if (t < 234) {
        const float* wf = (const float*)wsu;   // uniform -> scalar loads
        const int g = t / 26, xcol = t - g * 26;
        const int y0 = 3 * g;
        float xv[5][3];
        #pragma unroll
        for (int r = 0; r < 5; ++r) {
            int rr = y0 + r; if (rr > 27) rr = 27;   // g=8 clamp (rows unused)
            #pragma unroll
            for (int c = 0; c < 3; ++c)
                xv[r][c] = xs[rr*28 + xcol + c];
        }
        v2f xp[9];
        #pragma unroll
        for (int ky = 0; ky < 3; ++ky)
            #pragma unroll
            for (int kx = 0; kx < 3; ++kx) {
                v2f p; p.x = xv[ky][kx]; p.y = xv[ky+1][kx];
                xp[ky*3+kx] = p;
            }
        uint m0 = 0, m1 = 0, m2 = 0;
        for (int oc = 0; oc < 16; ++oc) {
            v2f s01 = {0.f, 0.f};
            float s2 = 0.f;
            #pragma unroll
            for (int ky = 0; ky < 3; ++ky)
                #pragma unroll
                for (int kx = 0; kx < 3; ++kx) {
                    float w = wf[oc*9 + ky*3 + kx];
                    s01 = xp[ky*3+kx] * w + s01;          // v_pk_fma_f32
                    s2  = fmaf(xv[ky + 2][kx], w, s2);
                }
            float s0 = s01.x, s1 = s01.y;
            bool b0 = (s0 >= 0.f), b1 = (s1 >= 0.f), b2 = (s2 >= 0.f);
            // fp32 accum error bound ~2.5e-5 << 1e-4: outside the band the
            // fp32 sign equals the exact (fp64) sign.
            if (__builtin_expect((int)((fabsf(s0) < 1e-4f) |
                                       (fabsf(s1) < 1e-4f) |
                                       (fabsf(s2) < 1e-4f)), 0)) {
                double d0 = 0.0, d1 = 0.0, d2 = 0.0;
                for (int k = 0; k < 9; ++k) {
                    double w = (double)wf[oc*9 + k];
                    d0 += (double)xv[k/3    ][k%3] * w;
                    d1 += (double)xv[k/3 + 1][k%3] * w;
                    d2 += (double)xv[k/3 + 2][k%3] * w;
                }
                b0 = (d0 >= 0.0); b1 = (d1 >= 0.0); b2 = (d2 >= 0.0);
            }
            m0 |= (uint)b0 << oc;
            m1 |= (uint)b1 << oc;
            m2 |= (uint)b2 << oc;
        }
        *(v4i*)(h1 + ((y0    )*26 + xcol)*16) = expand16(m0);
        *(v4i*)(h1 + ((y0 + 1)*26 + xcol)*16) = expand16(m1);
        if (y0 + 2 <= 25)
            *(v4i*)(h1 + ((y0 + 2)*26 + xcol)*16) = expand16(m2);
    }
    __syncthreads();

    // ---- conv2 via i8 MFMA, SWAPPED operands: D[oc][pos] ----
    // A = W2 frags (regs), B = h1 b128 loads (same bytes as before).
    // Lane holds 16 oc-signs of its own position -> in-register mask build.
    {
        const v4i* w2bp = (const v4i*)(wsu + WS_W2B);
        v4i b2f[5];
        #pragma unroll
        for (int s = 0; s < 5; ++s) b2f[s] = w2bp[s*64 + l];
        for (int tile = wave; tile < 18; tile += 4) {
            const int mb = tile * 32;
            const int row = mb + lane31;
            const int y = row / 24, xx = row % 24;
            v16i acc = {0,0,0,0,0,0,0,0,0,0,0,0,0,0,0,0};
            #pragma unroll
            for (int s = 0; s < 5; ++s) {
                int tap = s*2 + half; if (tap > 8) tap = 8;  // W zeroed for tap 9
                int ky = tap / 3, kx = tap - ky*3;
                v4i b = *(const v4i*)(h1 + ((y+ky)*26 + xx+kx)*16);
                acc = __builtin_amdgcn_mfma_i32_32x32x32_i8(b2f[s], b, acc, 0, 0, 0);
            }
            uint mneg = 0;
            #pragma unroll
            for (int r = 0; r < 16; ++r)
                mneg |= (((uint)acc[r]) >> 31) << r;   // bit r = sign(oc(r,half))
            h2u[row*2 + half] = (u16)~mneg;
        }
    }
    __syncthreads();

    // ---- expand h2w -> h2 i8[2][576][16] (permuted-nibble unpack) ----
    for (int p = t; p < 576; p += 256) {
        uint w = h2w[p];
        v4i lo, hi;
        lo[0] = expand4( w        & 0xFu);
        lo[1] = expand4((w >> 16) & 0xFu);
        lo[2] = expand4((w >>  4) & 0xFu);
        lo[3] = expand4((w >> 20) & 0xFu);
        hi[0] = expand4((w >>  8) & 0xFu);
        hi[1] = expand4((w >> 24) & 0xFu);
        hi[2] = expand4((w >> 12) & 0xFu);
        hi[3] = expand4((w >> 28) & 0xFu);
        *(v4i*)(h2 + p*16)        = lo;   // ic 0-15
        *(v4i*)(h2 + 9216 + p*16) = hi;   // ic 16-31
    }
    __syncthreads();

    // ---- conv3 via i8 MFMA, SWAPPED operands: D[oc][pos] ----
    {
        const v4i* w3bp = (const v4i*)(wsu + WS_W3B);
        v4i b3f[9];
        #pragma unroll
        for (int s = 0; s < 9; ++s) b3f[s] = w3bp[s*64 + l];
        const signed char* h2h = h2 + half*9216;
        for (int tile = wave; tile < 16; tile += 4) {
            const int mb = tile * 32;
            int row = mb + lane31;
            int pr = (row < 484) ? row : 483;
            const int y = pr / 22, xx = pr % 22;
            v16i acc = {0,0,0,0,0,0,0,0,0,0,0,0,0,0,0,0};
            #pragma unroll
            for (int s = 0; s < 9; ++s) {
                const int ky = s / 3, kx = s - ky*3;
                v4i b = *(const v4i*)(h2h + ((y+ky)*24 + xx+kx)*16);
                acc = __builtin_amdgcn_mfma_i32_32x32x32_i8(b3f[s], b, acc, 0, 0, 0);
            }
            uint mneg = 0;
            #pragma unroll
            for (int r = 0; r < 16; ++r)
                mneg |= (((uint)acc[r]) >> 31) << r;
            if (row < 484) h3u[row*2 + half] = (u16)~mneg;
        }
    }
    __syncthreads();

    // ---- avgpool + FC as binary dot (permuted bits match wfc packing) ----
    uint acc5[5] = {0u, 0u, 0u, 0u, 0u};
    for (int p = t; p < 484; p += 256) {
        uint h = h3[p];
        const uint* wp = wsu + WS_FC + p;
        #pragma unroll
        for (int o = 0; o < 5; ++o)
            acc5[o] += (uint)__popc(h ^ wp[(2*o)*484])
                     + ((uint)__popc(h ^ wp[(2*o+1)*484]) << 16);
    }
    #pragma unroll
    for (int o = 0; o < 5; ++o) {
        uint v = acc5[o];
        v += __shfl_down(v, 32); v += __shfl_down(v, 16);
        v += __shfl_down(v, 8);  v += __shfl_down(v, 4);
        v += __shfl_down(v, 2);  v += __shfl_down(v, 1);
        acc5[o] = v;
    }
    if (l == 0) {
        #pragma unroll
        for (int o = 0; o < 5; ++o) red[wave][o] = acc5[o];
    }
    __syncthreads();
    if (t < 10) {
        uint S = 0;
        #pragma unroll
        for (int j = 0; j < 4; ++j) {
            uint w = red[j][t >> 1];
            S += (t & 1) ? (w >> 16) : (w & 0xFFFFu);
        }
        lg[t] = 0.25f * (float)(15488 - 2*(int)S) + bfc[t];
    }
    __syncthreads();
    if (t < 10) {
        float m = lg[0];
        #pragma unroll
        for (int o = 1; o < 10; ++o) m = fmaxf(m, lg[o]);
        float se = 0.f;
        #pragma unroll
        for (int o = 0; o < 10; ++o) se += expf(lg[o] - m);
        out[(size_t)img*10 + t] = lg[t] - m - logf(se);
    }
}

extern "C" void kernel_launch(void* const* d_in, const int* in_sizes, int n_in,
                              void* d_out, int out_size, void* d_ws, size_t ws_size,
                              hipStream_t stream)
{
    const float* x   = (const float*)d_in[0];
    const float* w1  = (const float*)d_in[1];
    const float* w2  = (const float*)d_in[2];
    const float* w3  = (const float*)d_in[3];
    const float* wfc = (const float*)d_in[4];
    const float* bfc = (const float*)d_in[5];
    float* out = (float*)d_out;
    uint* wsu  = (uint*)d_ws;

    const int B = in_sizes[0] / 784;   // 8192

    hipLaunchKernelGGL(pack_kernel, dim3(23), dim3(256), 0, stream,
                       w1, w2, w3, wfc, wsu);
    hipLaunchKernelGGL(binet_kernel, dim3(B), dim3(256), 0, stream,
                       x, wsu, bfc, out);
}